// Round 2
// baseline (4897.575 us; speedup 1.0000x reference)
//
#include <hip/hip_runtime.h>
#include <hip/hip_fp16.h>

#define NB 64
#define NT 512
#define ND 128
#define NH 256
#define G4 1024                     // 4*H
#define NBT (NB*NT)                 // 32768
#define CSTRIDE ((size_t)NBT * G4)  // elements per interval component of px

typedef _Float16 f16x2 __attribute__((ext_vector_type(2)));

__device__ __forceinline__ float fdot2u(unsigned a, unsigned b, float c) {
  return __builtin_amdgcn_fdot2(__builtin_bit_cast(f16x2, a),
                                __builtin_bit_cast(f16x2, b), c, false);
}

// 8 f16 MACs per component: val += w.h, mid += w.h, rad += |w|.h
__device__ __forceinline__ void acc8(uint4 w, uint4 hv, uint4 hm, uint4 hr,
                                     float& av, float& am, float& ar) {
  const unsigned M = 0x7FFF7FFFu;
  av = fdot2u(w.x, hv.x, av); am = fdot2u(w.x, hm.x, am); ar = fdot2u(w.x & M, hr.x, ar);
  av = fdot2u(w.y, hv.y, av); am = fdot2u(w.y, hm.y, am); ar = fdot2u(w.y & M, hr.y, ar);
  av = fdot2u(w.z, hv.z, av); am = fdot2u(w.z, hm.z, am); ar = fdot2u(w.z & M, hr.z, ar);
  av = fdot2u(w.w, hv.w, av); am = fdot2u(w.w, hm.w, am); ar = fdot2u(w.w & M, hr.w, ar);
}

// all-reduce across the 4 lanes of a quad via DPP quad_perm (no LDS pipe)
__device__ __forceinline__ float qsum4(float x) {
  int v = __builtin_amdgcn_update_dpp(0, __builtin_bit_cast(int, x), 0xB1, 0xF, 0xF, true); // xor1
  x += __builtin_bit_cast(float, v);
  v = __builtin_amdgcn_update_dpp(0, __builtin_bit_cast(int, x), 0x4E, 0xF, 0xF, true);     // xor2
  x += __builtin_bit_cast(float, v);
  return x;
}

__device__ __forceinline__ float sel4(float x0, float x1, float x2, float x3, int q) {
  float a = (q & 1) ? x1 : x0;
  float b = (q & 1) ? x3 : x2;
  return (q & 2) ? b : a;
}

__device__ __forceinline__ float rcpf(float x) { return __builtin_amdgcn_rcpf(x); }
// sigmoid or tanh, branchless: tanh(x) = 2*sigmoid(2x)-1
__device__ __forceinline__ float gact(float x, bool is_tanh) {
  float s = is_tanh ? -2.0f : -1.0f;
  float e = __expf(s * x);
  float r = rcpf(1.0f + e);
  return is_tanh ? fmaf(2.0f, r, -1.0f) : r;
}
__device__ __forceinline__ float tanh_f(float x) {
  return fmaf(2.0f, rcpf(1.0f + __expf(-2.0f * x)), -1.0f);
}

// Repack weights (f32 -> f16) into the per-thread K-split layout.
// WqHH2[(c*8+r)*512 + t]: uint4 = Whh[j = (t>>2)*8+r][8*k8 .. +8], k8 = (t&3)*8 + c  (c,r in 0..7)
// WqIH2[(c*8+r)*512 + t]: uint4 = Wih[j = (t>>2)*8+r][8*k8 .. +8], k8 = (t&3)*4 + c  (c in 0..3)
__global__ void conv_w_kernel(const float* __restrict__ Whh, const float* __restrict__ Wih,
                              uint4* __restrict__ WqHH2, uint4* __restrict__ WqIH2) {
  int o = blockIdx.x * 256 + threadIdx.x;
  union { uint4 u; __half h[8]; } p;
  if (o < 32768) {
    int t = o & 511, rc = o >> 9, c = rc >> 3, r = rc & 7;
    int j = ((t >> 2) << 3) + r, k8 = ((t & 3) << 3) + c;
    const float* s = Whh + j * NH + k8 * 8;
#pragma unroll
    for (int i = 0; i < 8; ++i) p.h[i] = __float2half(s[i]);
    WqHH2[o] = p.u;
  } else if (o < 32768 + 16384) {
    int o2 = o - 32768;
    int t = o2 & 511, rc = o2 >> 9, c = rc >> 3, r = rc & 7;
    int j = ((t >> 2) << 3) + r, k8 = ((t & 3) << 2) + c;
    const float* s = Wih + j * ND + k8 * 8;
#pragma unroll
    for (int i = 0; i < 8; ++i) p.h[i] = __float2half(s[i]);
    WqIH2[o2] = p.u;
  }
}

// px[(comp, bt, j)] = interval-linear of x with W_ih (no bias), f16.
// Block = 32 bt-rows. Thread t: K-quarter q=t&3 (32 elems), dot-rows (t>>2)*8 .. +7,
// writer rows 2t, 2t+1. Weights VGPR-resident across all 32 rows.
__global__ __launch_bounds__(512, 2)
void px_kernel(const float* __restrict__ xv, const float* __restrict__ xl,
               const float* __restrict__ xu, const uint4* __restrict__ WqIH2,
               __half* __restrict__ px) {
  __shared__ __align__(16) __half sv[32 * ND];
  __shared__ __align__(16) __half sm[32 * ND];
  __shared__ __align__(16) __half sr[32 * ND];
  const int t = threadIdx.x;
  const int q = t & 3;
  const int r0 = blockIdx.x * 32;
  uint4 w[4][8];
#pragma unroll
  for (int c = 0; c < 4; ++c)
#pragma unroll
    for (int r = 0; r < 8; ++r)
      w[c][r] = WqIH2[((c * 8 + r) << 9) + t];
  {
    const float4* v4 = (const float4*)(xv + (size_t)r0 * ND);
    const float4* l4 = (const float4*)(xl + (size_t)r0 * ND);
    const float4* u4 = (const float4*)(xu + (size_t)r0 * ND);
    __half2* sv2 = (__half2*)sv; __half2* sm2 = (__half2*)sm; __half2* sr2 = (__half2*)sr;
    for (int i = t; i < 1024; i += 512) {
      float4 v = v4[i], l = l4[i], u = u4[i];
      sv2[2*i]   = __floats2half2_rn(v.x, v.y);
      sv2[2*i+1] = __floats2half2_rn(v.z, v.w);
      sm2[2*i]   = __floats2half2_rn(0.5f*(l.x+u.x), 0.5f*(l.y+u.y));
      sm2[2*i+1] = __floats2half2_rn(0.5f*(l.z+u.z), 0.5f*(l.w+u.w));
      sr2[2*i]   = __floats2half2_rn(0.5f*(u.x-l.x), 0.5f*(u.y-l.y));
      sr2[2*i+1] = __floats2half2_rn(0.5f*(u.z-l.z), 0.5f*(u.w-l.w));
    }
  }
  __syncthreads();
  const uint4* bv = (const uint4*)sv;
  const uint4* bm = (const uint4*)sm;
  const uint4* br = (const uint4*)sr;
  for (int rr = 0; rr < 32; ++rr) {
    uint4 hv[4], hm[4], hr[4];
    const int base = rr * 16 + q * 4;
#pragma unroll
    for (int i = 0; i < 4; ++i) { hv[i] = bv[base+i]; hm[i] = bm[base+i]; hr[i] = br[base+i]; }
    float A[8][3];
#pragma unroll
    for (int r = 0; r < 8; ++r) { A[r][0] = 0.f; A[r][1] = 0.f; A[r][2] = 0.f; }
#pragma unroll
    for (int c = 0; c < 4; ++c)
#pragma unroll
      for (int r = 0; r < 8; ++r)
        acc8(w[c][r], hv[c], hm[c], hr[c], A[r][0], A[r][1], A[r][2]);
#pragma unroll
    for (int r = 0; r < 8; ++r) {
      A[r][0] = qsum4(A[r][0]); A[r][1] = qsum4(A[r][1]); A[r][2] = qsum4(A[r][2]);
    }
    float v0 = sel4(A[0][0], A[2][0], A[4][0], A[6][0], q);
    float m0 = sel4(A[0][1], A[2][1], A[4][1], A[6][1], q);
    float d0 = sel4(A[0][2], A[2][2], A[4][2], A[6][2], q);
    float v1 = sel4(A[1][0], A[3][0], A[5][0], A[7][0], q);
    float m1 = sel4(A[1][1], A[3][1], A[5][1], A[7][1], q);
    float d1 = sel4(A[1][2], A[3][2], A[5][2], A[7][2], q);
    size_t ob = (size_t)(r0 + rr) * G4;
    ((__half2*)(px + ob))[t]             = __floats2half2_rn(v0, v1);
    ((__half2*)(px + CSTRIDE + ob))[t]   = __floats2half2_rn(m0 - d0, m1 - d1);
    ((__half2*)(px + 2*CSTRIDE + ob))[t] = __floats2half2_rn(m0 + d0, m1 + d1);
  }
}

// Recurrence: one block per batch row, 512 threads.
// Thread t: K-quarter q=t&3 (64 h-elems, VGPR-resident per step), dot-rows (t>>2)*8..+7,
// DPP quad butterfly reduce, writer rows 2t,2t+1. c-state in cell-thread registers.
// h stored in LDS as 4 q-slices padded 144 B apart (conflict-free quad reads).
__global__ __launch_bounds__(512, 2)
void lstm_kernel(const uint4* __restrict__ Wq2, const __half* __restrict__ px,
                 const float* __restrict__ bias, float* __restrict__ out) {
  __shared__ __align__(16) __half sHV[288];   // 4 slices x 72 halfs (64 used + 8 pad)
  __shared__ __align__(16) __half sHM[288];
  __shared__ __align__(16) __half sHR[288];
  __shared__ __align__(16) float sA[3][G4];
  const int t = threadIdx.x;
  const int b = blockIdx.x;
  const int q = t & 3;
  const float2 bb = ((const float2*)bias)[t];      // bias for rows 2t, 2t+1
  const bool is_tanh = ((t >> 7) == 2);            // rows 512..767 = gate g
  if (t < 144) { ((unsigned*)sHV)[t] = 0u; ((unsigned*)sHM)[t] = 0u; ((unsigned*)sHR)[t] = 0u; }
  float cv = 0.f, cl = 0.f, cu = 0.f;              // cell state (threads 0..255)
  __syncthreads();
  const __half* pxb = px + (size_t)b * NT * G4;
  float* outb = out + (size_t)b * NT * NH;
  const uint4* hvB = (const uint4*)sHV + q * 9;    // q*144 bytes
  const uint4* hmB = (const uint4*)sHM + q * 9;
  const uint4* hrB = (const uint4*)sHR + q * 9;
  for (int ts = 0; ts < NT; ++ts) {
    const __half* pxt = pxb + (size_t)ts * G4;
    __half2 pv2 = ((const __half2*)pxt)[t];
    __half2 pl2 = ((const __half2*)(pxt + CSTRIDE))[t];
    __half2 pu2 = ((const __half2*)(pxt + 2*CSTRIDE))[t];
    uint4 hv[8], hm[8], hr[8];
#pragma unroll
    for (int i = 0; i < 8; ++i) { hv[i] = hvB[i]; hm[i] = hmB[i]; hr[i] = hrB[i]; }
    float A[8][3];
#pragma unroll
    for (int r = 0; r < 8; ++r) { A[r][0] = 0.f; A[r][1] = 0.f; A[r][2] = 0.f; }
#pragma unroll
    for (int c = 0; c < 8; ++c)
#pragma unroll
      for (int r = 0; r < 8; ++r) {
        uint4 w = Wq2[((c * 8 + r) << 9) + t];     // contiguous 1 KiB per wave-load
        acc8(w, hv[c], hm[c], hr[c], A[r][0], A[r][1], A[r][2]);
      }
#pragma unroll
    for (int r = 0; r < 8; ++r) {
      A[r][0] = qsum4(A[r][0]); A[r][1] = qsum4(A[r][1]); A[r][2] = qsum4(A[r][2]);
    }
    float v0 = sel4(A[0][0], A[2][0], A[4][0], A[6][0], q);
    float m0 = sel4(A[0][1], A[2][1], A[4][1], A[6][1], q);
    float d0 = sel4(A[0][2], A[2][2], A[4][2], A[6][2], q);
    float v1 = sel4(A[1][0], A[3][0], A[5][0], A[7][0], q);
    float m1 = sel4(A[1][1], A[3][1], A[5][1], A[7][1], q);
    float d1 = sel4(A[1][2], A[3][2], A[5][2], A[7][2], q);
    // pre-activations for rows 2t, 2t+1 (val, lb, ub) then activation
    float g00 = gact(__low2float(pv2)  + bb.x + v0, is_tanh);
    float g01 = gact(__low2float(pl2)  + bb.x + (m0 - d0), is_tanh);
    float g02 = gact(__low2float(pu2)  + bb.x + (m0 + d0), is_tanh);
    float g10 = gact(__high2float(pv2) + bb.y + v1, is_tanh);
    float g11 = gact(__high2float(pl2) + bb.y + (m1 - d1), is_tanh);
    float g12 = gact(__high2float(pu2) + bb.y + (m1 + d1), is_tanh);
    ((float2*)&sA[0][0])[t] = make_float2(g00, g10);
    ((float2*)&sA[1][0])[t] = make_float2(g01, g11);
    ((float2*)&sA[2][0])[t] = make_float2(g02, g12);
    __syncthreads();
    if (t < NH) {
      float iv = sA[0][t],        il = sA[1][t],        iu = sA[2][t];
      float fv = sA[0][NH+t],     fl = sA[1][NH+t],     fu = sA[2][NH+t];
      float gv = sA[0][2*NH+t],   gl = sA[1][2*NH+t],   gu = sA[2][2*NH+t];
      float ov = sA[0][3*NH+t],   ol = sA[1][3*NH+t],   ou = sA[2][3*NH+t];
      float p0 = fl*cl, p1 = fl*cu, p2 = fu*cl, p3 = fu*cu;
      float fcl = fminf(fminf(p0,p1), fminf(p2,p3));
      float fcu = fmaxf(fmaxf(p0,p1), fmaxf(p2,p3));
      float fcv = fv*cv;
      p0 = il*gl; p1 = il*gu; p2 = iu*gl; p3 = iu*gu;
      float igl = fminf(fminf(p0,p1), fminf(p2,p3));
      float igu = fmaxf(fmaxf(p0,p1), fmaxf(p2,p3));
      cv = fcv + iv*gv; cl = fcl + igl; cu = fcu + igu;
      float tv = tanh_f(cv), tl = tanh_f(cl), tu = tanh_f(cu);
      float hvn = ov*tv;
      p0 = ol*tl; p1 = ol*tu; p2 = ou*tl; p3 = ou*tu;
      float hl = fminf(fminf(p0,p1), fminf(p2,p3));
      float hu = fmaxf(fmaxf(p0,p1), fmaxf(p2,p3));
      outb[(size_t)ts*NH + t] = hvn;
      outb[(size_t)NBT*NH + (size_t)ts*NH + t] = hl;
      outb[2*(size_t)NBT*NH + (size_t)ts*NH + t] = hu;
      int hidx = (t >> 6) * 72 + (t & 63);
      sHV[hidx] = __float2half(hvn);
      sHM[hidx] = __float2half(0.5f * (hl + hu));
      sHR[hidx] = __float2half(0.5f * (hu - hl));
    }
    __syncthreads();
  }
}

extern "C" void kernel_launch(void* const* d_in, const int* in_sizes, int n_in,
                              void* d_out, int out_size, void* d_ws, size_t ws_size,
                              hipStream_t stream) {
  const float* xv   = (const float*)d_in[0];
  const float* xl   = (const float*)d_in[1];
  const float* xu   = (const float*)d_in[2];
  const float* Wih  = (const float*)d_in[3];
  const float* Whh  = (const float*)d_in[4];
  const float* bias = (const float*)d_in[5];
  float* out = (float*)d_out;
  char* ws = (char*)d_ws;
  uint4*  WqHH2 = (uint4*)ws;                  // 512 KiB
  uint4*  WqIH2 = (uint4*)(ws + 512 * 1024);   // 256 KiB
  __half* px    = (__half*)(ws + 768 * 1024);  // 3 * 32768 * 1024 * 2 B = 192 MiB

  conv_w_kernel<<<192, 256, 0, stream>>>(Whh, Wih, WqHH2, WqIH2);
  px_kernel<<<NBT / 32, 512, 0, stream>>>(xv, xl, xu, WqIH2, px);
  lstm_kernel<<<NB, 512, 0, stream>>>(WqHH2, px, bias, out);
}

// Round 3
// 4093.188 us; speedup vs baseline: 1.1965x; 1.1965x over previous
//
#include <hip/hip_runtime.h>
#include <hip/hip_fp16.h>

#define NB 64
#define NT 512
#define ND 128
#define NH 256
#define G4 1024                     // 4*H
#define NBT (NB*NT)                 // 32768
#define CSTRIDE ((size_t)NBT * G4)  // elements per interval component of px
#define OSTRIDE ((size_t)NBT * NH)  // elements per interval component of out

typedef _Float16 f16x2 __attribute__((ext_vector_type(2)));

__device__ __forceinline__ float fdot2u(unsigned a, unsigned b, float c) {
  return __builtin_amdgcn_fdot2(__builtin_bit_cast(f16x2, a),
                                __builtin_bit_cast(f16x2, b), c, false);
}

// 8 f16 MACs per component: val += w.h, mid += w.h, rad += |w|.h
__device__ __forceinline__ void acc8(uint4 w, uint4 hv, uint4 hm, uint4 hr,
                                     float& av, float& am, float& ar) {
  const unsigned M = 0x7FFF7FFFu;
  av = fdot2u(w.x, hv.x, av); am = fdot2u(w.x, hm.x, am); ar = fdot2u(w.x & M, hr.x, ar);
  av = fdot2u(w.y, hv.y, av); am = fdot2u(w.y, hm.y, am); ar = fdot2u(w.y & M, hr.y, ar);
  av = fdot2u(w.z, hv.z, av); am = fdot2u(w.z, hm.z, am); ar = fdot2u(w.z & M, hr.z, ar);
  av = fdot2u(w.w, hv.w, av); am = fdot2u(w.w, hm.w, am); ar = fdot2u(w.w & M, hr.w, ar);
}

// all-reduce across the 4 lanes of a quad via DPP quad_perm (verified R2)
__device__ __forceinline__ float qsum4(float x) {
  int v = __builtin_amdgcn_update_dpp(0, __builtin_bit_cast(int, x), 0xB1, 0xF, 0xF, true);
  x += __builtin_bit_cast(float, v);
  v = __builtin_amdgcn_update_dpp(0, __builtin_bit_cast(int, x), 0x4E, 0xF, 0xF, true);
  x += __builtin_bit_cast(float, v);
  return x;
}

__device__ __forceinline__ float sel4(float x0, float x1, float x2, float x3, int q) {
  float a = (q & 1) ? x1 : x0;
  float b = (q & 1) ? x3 : x2;
  return (q & 2) ? b : a;
}
__device__ __forceinline__ unsigned usel4(unsigned x0, unsigned x1, unsigned x2, unsigned x3, int q) {
  unsigned a = (q & 1) ? x1 : x0;
  unsigned b = (q & 1) ? x3 : x2;
  return (q & 2) ? b : a;
}

__device__ __forceinline__ float rcpf(float x) { return __builtin_amdgcn_rcpf(x); }
__device__ __forceinline__ float gact(float x, bool is_tanh) {
  float s = is_tanh ? -2.0f : -1.0f;
  float e = __expf(s * x);
  float r = rcpf(1.0f + e);
  return is_tanh ? fmaf(2.0f, r, -1.0f) : r;
}
__device__ __forceinline__ float tanh_f(float x) {
  return fmaf(2.0f, rcpf(1.0f + __expf(-2.0f * x)), -1.0f);
}

// Pack weights f32->f16.
// PA[(r*8+c8)*512+t]  = Whh[(t>>2)*8 + r     ][(t&3)*64 + c8*8 ..+8]   r=0..3 (VGPR rows)
// PB[(c*8+r2*2+hf)*512+t] = Whh[(t>>2)*8+4+r2][(t&3)*64 + c*16 + hf*8 ..+8] (streamed rows)
// PIH[(c*8+r)*512+t]  = Wih[(t>>2)*8 + r     ][(t&3)*32 + c*8 ..+8]   (px kernel, as R2)
__global__ void conv_w_kernel(const float* __restrict__ Whh, const float* __restrict__ Wih,
                              uint4* __restrict__ PA, uint4* __restrict__ PB,
                              uint4* __restrict__ PIH) {
  int o = blockIdx.x * 256 + threadIdx.x;
  union { uint4 u; __half h[8]; } p;
  if (o < 16384) {
    int t = o & 511, rc = o >> 9, r = rc >> 3, c8 = rc & 7;
    int j = ((t >> 2) << 3) + r, k = ((t & 3) << 6) + c8 * 8;
    const float* s = Whh + j * NH + k;
#pragma unroll
    for (int i = 0; i < 8; ++i) p.h[i] = __float2half(s[i]);
    PA[o] = p.u;
  } else if (o < 32768) {
    int o2 = o - 16384;
    int t = o2 & 511, rc = o2 >> 9, c = rc >> 3, r2 = (rc >> 1) & 3, hf = rc & 1;
    int j = ((t >> 2) << 3) + 4 + r2, k = ((t & 3) << 6) + c * 16 + hf * 8;
    const float* s = Whh + j * NH + k;
#pragma unroll
    for (int i = 0; i < 8; ++i) p.h[i] = __float2half(s[i]);
    PB[o2] = p.u;
  } else if (o < 49152) {
    int o3 = o - 32768;
    int t = o3 & 511, rc = o3 >> 9, c = rc >> 3, r = rc & 7;
    int j = ((t >> 2) << 3) + r, k = ((t & 3) << 5) + c * 8;
    const float* s = Wih + j * ND + k;
#pragma unroll
    for (int i = 0; i < 8; ++i) p.h[i] = __float2half(s[i]);
    PIH[o3] = p.u;
  }
}

// px kernel: unchanged structure from R2 (passed; VGPR-resident W_ih, quad reduce).
__global__ __launch_bounds__(512, 2)
void px_kernel(const float* __restrict__ xv, const float* __restrict__ xl,
               const float* __restrict__ xu, const uint4* __restrict__ PIH,
               __half* __restrict__ px) {
  __shared__ __align__(16) __half sv[32 * ND];
  __shared__ __align__(16) __half sm[32 * ND];
  __shared__ __align__(16) __half sr[32 * ND];
  const int t = threadIdx.x;
  const int q = t & 3;
  const int r0 = blockIdx.x * 32;
  uint4 w[4][8];
#pragma unroll
  for (int c = 0; c < 4; ++c)
#pragma unroll
    for (int r = 0; r < 8; ++r)
      w[c][r] = PIH[((c * 8 + r) << 9) + t];
  {
    const float4* v4 = (const float4*)(xv + (size_t)r0 * ND);
    const float4* l4 = (const float4*)(xl + (size_t)r0 * ND);
    const float4* u4 = (const float4*)(xu + (size_t)r0 * ND);
    __half2* sv2 = (__half2*)sv; __half2* sm2 = (__half2*)sm; __half2* sr2 = (__half2*)sr;
    for (int i = t; i < 1024; i += 512) {
      float4 v = v4[i], l = l4[i], u = u4[i];
      sv2[2*i]   = __floats2half2_rn(v.x, v.y);
      sv2[2*i+1] = __floats2half2_rn(v.z, v.w);
      sm2[2*i]   = __floats2half2_rn(0.5f*(l.x+u.x), 0.5f*(l.y+u.y));
      sm2[2*i+1] = __floats2half2_rn(0.5f*(l.z+u.z), 0.5f*(l.w+u.w));
      sr2[2*i]   = __floats2half2_rn(0.5f*(u.x-l.x), 0.5f*(u.y-l.y));
      sr2[2*i+1] = __floats2half2_rn(0.5f*(u.z-l.z), 0.5f*(u.w-l.w));
    }
  }
  __syncthreads();
  const uint4* bv = (const uint4*)sv;
  const uint4* bm = (const uint4*)sm;
  const uint4* br = (const uint4*)sr;
  for (int rr = 0; rr < 32; ++rr) {
    uint4 hv[4], hm[4], hr[4];
    const int base = rr * 16 + q * 4;
#pragma unroll
    for (int i = 0; i < 4; ++i) { hv[i] = bv[base+i]; hm[i] = bm[base+i]; hr[i] = br[base+i]; }
    float A[8][3];
#pragma unroll
    for (int r = 0; r < 8; ++r) { A[r][0] = 0.f; A[r][1] = 0.f; A[r][2] = 0.f; }
#pragma unroll
    for (int c = 0; c < 4; ++c)
#pragma unroll
      for (int r = 0; r < 8; ++r)
        acc8(w[c][r], hv[c], hm[c], hr[c], A[r][0], A[r][1], A[r][2]);
#pragma unroll
    for (int r = 0; r < 8; ++r) {
      A[r][0] = qsum4(A[r][0]); A[r][1] = qsum4(A[r][1]); A[r][2] = qsum4(A[r][2]);
    }
    float v0 = sel4(A[0][0], A[2][0], A[4][0], A[6][0], q);
    float m0 = sel4(A[0][1], A[2][1], A[4][1], A[6][1], q);
    float d0 = sel4(A[0][2], A[2][2], A[4][2], A[6][2], q);
    float v1 = sel4(A[1][0], A[3][0], A[5][0], A[7][0], q);
    float m1 = sel4(A[1][1], A[3][1], A[5][1], A[7][1], q);
    float d1 = sel4(A[1][2], A[3][2], A[5][2], A[7][2], q);
    size_t ob = (size_t)(r0 + rr) * G4;
    ((__half2*)(px + ob))[t]             = __floats2half2_rn(v0, v1);
    ((__half2*)(px + CSTRIDE + ob))[t]   = __floats2half2_rn(m0 - d0, m1 - d1);
    ((__half2*)(px + 2*CSTRIDE + ob))[t] = __floats2half2_rn(m0 + d0, m1 + d1);
  }
}

// Recurrence: one block per batch row, 512 threads, q=t&3 K-quarter, g=t>>2.
// Thread owns 8 gate rows g*8..g*8+7: rows +0..3 have W VGPR-RESIDENT (128 regs),
// rows +4..7 streamed from L2 per step (256 KiB/block/step, prefetch at chunk top).
// h in LDS as q-padded slices (4-distinct-addr broadcast reads, no conflicts).
__global__ __launch_bounds__(512, 2)
void lstm_kernel(const uint4* __restrict__ PA, const uint4* __restrict__ PB,
                 const __half* __restrict__ px, const float* __restrict__ bias,
                 float* __restrict__ out) {
  __shared__ __align__(16) __half sH[3][4][72];   // [comp][q][64 + 8 pad]
  __shared__ __align__(16) float sG[3][G4];       // activated gates
  const int t = threadIdx.x;
  const int b = blockIdx.x;
  const int q = t & 3;
  const int g = t >> 2;
  // VGPR-resident W rows g*8+0..3, full K-quarter
  uint4 Wv[4][8];
#pragma unroll
  for (int r = 0; r < 4; ++r)
#pragma unroll
    for (int c8 = 0; c8 < 8; ++c8)
      Wv[r][c8] = PA[((r * 8 + c8) << 9) + t];
  const float2 bb = ((const float2*)bias)[g * 4 + q];  // rows g*8+2q, +1
  const bool is_tanh = ((g >> 5) == 2);                // rows 512..767 = gate g
  if (t < 432) ((unsigned*)sH)[t] = 0u;                // 3*4*72 halfs = 432 dwords/2... (864B=216 dw) safe overshoot below
  if (t < 216) ((unsigned*)(&sH[0][0][0]))[t] = 0u;
  float cv = 0.f, cl = 0.f, cu = 0.f;                  // cell state (t<256)
  __syncthreads();
  const __half* pxb = px + (size_t)b * NT * G4 + g * 8;
  float* outb = out + (size_t)b * NT * NH;
  for (int ts = 0; ts < NT; ++ts) {
    const __half* pxt = pxb + (size_t)ts * G4;
    uint4 pxV = *(const uint4*)(pxt);
    uint4 pxL = *(const uint4*)(pxt + CSTRIDE);
    uint4 pxU = *(const uint4*)(pxt + 2 * CSTRIDE);
    float A[8][3];
#pragma unroll
    for (int r = 0; r < 8; ++r) { A[r][0] = 0.f; A[r][1] = 0.f; A[r][2] = 0.f; }
#pragma unroll
    for (int c = 0; c < 4; ++c) {                      // 16-h chunks of the K-quarter
      // streamed rows g*8+4..7, this chunk: 8 contiguous wave-loads (8 KiB apart)
      uint4 wb[4][2];
#pragma unroll
      for (int r2 = 0; r2 < 4; ++r2) {
        wb[r2][0] = PB[((c * 8 + r2 * 2 + 0) << 9) + t];
        wb[r2][1] = PB[((c * 8 + r2 * 2 + 1) << 9) + t];
      }
      // h chunk: 2 uint4 per comp from q-slice (16 lanes/addr broadcast)
      const uint4* hv4 = (const uint4*)(&sH[0][q][0]) + c * 2;
      const uint4* hm4 = (const uint4*)(&sH[1][q][0]) + c * 2;
      const uint4* hr4 = (const uint4*)(&sH[2][q][0]) + c * 2;
      uint4 hv0 = hv4[0], hv1 = hv4[1];
      uint4 hm0 = hm4[0], hm1 = hm4[1];
      uint4 hr0 = hr4[0], hr1 = hr4[1];
      // VGPR rows first (covers L2 latency of wb)
#pragma unroll
      for (int r = 0; r < 4; ++r) {
        acc8(Wv[r][c * 2 + 0], hv0, hm0, hr0, A[r][0], A[r][1], A[r][2]);
        acc8(Wv[r][c * 2 + 1], hv1, hm1, hr1, A[r][0], A[r][1], A[r][2]);
      }
#pragma unroll
      for (int r2 = 0; r2 < 4; ++r2) {
        acc8(wb[r2][0], hv0, hm0, hr0, A[4 + r2][0], A[4 + r2][1], A[4 + r2][2]);
        acc8(wb[r2][1], hv1, hm1, hr1, A[4 + r2][0], A[4 + r2][1], A[4 + r2][2]);
      }
    }
#pragma unroll
    for (int r = 0; r < 8; ++r) {
      A[r][0] = qsum4(A[r][0]); A[r][1] = qsum4(A[r][1]); A[r][2] = qsum4(A[r][2]);
    }
    // writer rows w0 = g*8+2q, w1 = w0+1
    float v0 = sel4(A[0][0], A[2][0], A[4][0], A[6][0], q);
    float m0 = sel4(A[0][1], A[2][1], A[4][1], A[6][1], q);
    float d0 = sel4(A[0][2], A[2][2], A[4][2], A[6][2], q);
    float v1 = sel4(A[1][0], A[3][0], A[5][0], A[7][0], q);
    float m1 = sel4(A[1][1], A[3][1], A[5][1], A[7][1], q);
    float d1 = sel4(A[1][2], A[3][2], A[5][2], A[7][2], q);
    // px for rows 2q, 2q+1 = dword q of the uint4
    __half2 pv2 = __builtin_bit_cast(__half2, usel4(pxV.x, pxV.y, pxV.z, pxV.w, q));
    __half2 pl2 = __builtin_bit_cast(__half2, usel4(pxL.x, pxL.y, pxL.z, pxL.w, q));
    __half2 pu2 = __builtin_bit_cast(__half2, usel4(pxU.x, pxU.y, pxU.z, pxU.w, q));
    float g00 = gact(__low2float(pv2)  + bb.x + v0, is_tanh);
    float g01 = gact(__low2float(pl2)  + bb.x + (m0 - d0), is_tanh);
    float g02 = gact(__low2float(pu2)  + bb.x + (m0 + d0), is_tanh);
    float g10 = gact(__high2float(pv2) + bb.y + v1, is_tanh);
    float g11 = gact(__high2float(pl2) + bb.y + (m1 - d1), is_tanh);
    float g12 = gact(__high2float(pu2) + bb.y + (m1 + d1), is_tanh);
    const int wi = g * 4 + q;                       // float2 index of row pair
    ((float2*)&sG[0][0])[wi] = make_float2(g00, g10);
    ((float2*)&sG[1][0])[wi] = make_float2(g01, g11);
    ((float2*)&sG[2][0])[wi] = make_float2(g02, g12);
    __syncthreads();
    if (t < NH) {
      float iv = sG[0][t],        il = sG[1][t],        iu = sG[2][t];
      float fv = sG[0][NH+t],     fl = sG[1][NH+t],     fu = sG[2][NH+t];
      float gv = sG[0][2*NH+t],   gl = sG[1][2*NH+t],   gu = sG[2][2*NH+t];
      float ov = sG[0][3*NH+t],   ol = sG[1][3*NH+t],   ou = sG[2][3*NH+t];
      float p0 = fl*cl, p1 = fl*cu, p2 = fu*cl, p3 = fu*cu;
      float fcl = fminf(fminf(p0,p1), fminf(p2,p3));
      float fcu = fmaxf(fmaxf(p0,p1), fmaxf(p2,p3));
      float fcv = fv*cv;
      p0 = il*gl; p1 = il*gu; p2 = iu*gl; p3 = iu*gu;
      float igl = fminf(fminf(p0,p1), fminf(p2,p3));
      float igu = fmaxf(fmaxf(p0,p1), fmaxf(p2,p3));
      cv = fcv + iv*gv; cl = fcl + igl; cu = fcu + igu;
      float tv = tanh_f(cv), tl = tanh_f(cl), tu = tanh_f(cu);
      float hvn = ov*tv;
      p0 = ol*tl; p1 = ol*tu; p2 = ou*tl; p3 = ou*tu;
      float hl = fminf(fminf(p0,p1), fminf(p2,p3));
      float hu = fmaxf(fmaxf(p0,p1), fmaxf(p2,p3));
      outb[(size_t)ts*NH + t] = hvn;
      outb[OSTRIDE + (size_t)ts*NH + t] = hl;
      outb[2*OSTRIDE + (size_t)ts*NH + t] = hu;
      const int hq = t >> 6, ho = t & 63;
      sH[0][hq][ho] = __float2half(hvn);
      sH[1][hq][ho] = __float2half(0.5f * (hl + hu));
      sH[2][hq][ho] = __float2half(0.5f * (hu - hl));
    }
    __syncthreads();
  }
}

extern "C" void kernel_launch(void* const* d_in, const int* in_sizes, int n_in,
                              void* d_out, int out_size, void* d_ws, size_t ws_size,
                              hipStream_t stream) {
  const float* xv   = (const float*)d_in[0];
  const float* xl   = (const float*)d_in[1];
  const float* xu   = (const float*)d_in[2];
  const float* Wih  = (const float*)d_in[3];
  const float* Whh  = (const float*)d_in[4];
  const float* bias = (const float*)d_in[5];
  float* out = (float*)d_out;
  char* ws = (char*)d_ws;
  uint4*  PA  = (uint4*)ws;                    // 256 KiB (VGPR rows)
  uint4*  PB  = (uint4*)(ws + 256 * 1024);     // 256 KiB (streamed rows)
  uint4*  PIH = (uint4*)(ws + 512 * 1024);     // 256 KiB (px weights)
  __half* px  = (__half*)(ws + 768 * 1024);    // 192 MiB

  conv_w_kernel<<<192, 256, 0, stream>>>(Whh, Wih, PA, PB, PIH);
  px_kernel<<<NBT / 32, 512, 0, stream>>>(xv, xl, xu, PIH, px);
  lstm_kernel<<<NB, 512, 0, stream>>>(PA, PB, px, bias, out);
}

// Round 4
// 2978.634 us; speedup vs baseline: 1.6442x; 1.3742x over previous
//
#include <hip/hip_runtime.h>
#include <hip/hip_fp16.h>

#define NB 64
#define NT 512
#define ND 128
#define NH 256
#define G4 1024                     // 4*H
#define NBT (NB*NT)                 // 32768
#define CSTRIDE ((size_t)NBT * G4)  // elements per interval component of px
#define OSTRIDE ((size_t)NBT * NH)  // elements per interval component of out

typedef _Float16 f16x2 __attribute__((ext_vector_type(2)));

__device__ __forceinline__ float fdot2u(unsigned a, unsigned b, float c) {
  return __builtin_amdgcn_fdot2(__builtin_bit_cast(f16x2, a),
                                __builtin_bit_cast(f16x2, b), c, false);
}

// 8 f16 MACs per component: val += w.h, mid += w.h, rad += |w|.h
__device__ __forceinline__ void acc8(uint4 w, uint4 hv, uint4 hm, uint4 hr,
                                     float& av, float& am, float& ar) {
  const unsigned M = 0x7FFF7FFFu;
  av = fdot2u(w.x, hv.x, av); am = fdot2u(w.x, hm.x, am); ar = fdot2u(w.x & M, hr.x, ar);
  av = fdot2u(w.y, hv.y, av); am = fdot2u(w.y, hm.y, am); ar = fdot2u(w.y & M, hr.y, ar);
  av = fdot2u(w.z, hv.z, av); am = fdot2u(w.z, hm.z, am); ar = fdot2u(w.z & M, hr.z, ar);
  av = fdot2u(w.w, hv.w, av); am = fdot2u(w.w, hm.w, am); ar = fdot2u(w.w & M, hr.w, ar);
}

// all-reduce across the 4 lanes of a quad via DPP quad_perm (verified R2/R3)
__device__ __forceinline__ float qsum4(float x) {
  int v = __builtin_amdgcn_update_dpp(0, __builtin_bit_cast(int, x), 0xB1, 0xF, 0xF, true);
  x += __builtin_bit_cast(float, v);
  v = __builtin_amdgcn_update_dpp(0, __builtin_bit_cast(int, x), 0x4E, 0xF, 0xF, true);
  x += __builtin_bit_cast(float, v);
  return x;
}

__device__ __forceinline__ float sel4(float x0, float x1, float x2, float x3, int q) {
  float a = (q & 1) ? x1 : x0;
  float b = (q & 1) ? x3 : x2;
  return (q & 2) ? b : a;
}
__device__ __forceinline__ unsigned usel4(unsigned x0, unsigned x1, unsigned x2, unsigned x3, int q) {
  unsigned a = (q & 1) ? x1 : x0;
  unsigned b = (q & 1) ? x3 : x2;
  return (q & 2) ? b : a;
}

__device__ __forceinline__ float rcpf(float x) { return __builtin_amdgcn_rcpf(x); }
__device__ __forceinline__ float gact(float x, bool is_tanh) {
  float s = is_tanh ? -2.0f : -1.0f;
  float e = __expf(s * x);
  float r = rcpf(1.0f + e);
  return is_tanh ? fmaf(2.0f, r, -1.0f) : r;
}
__device__ __forceinline__ float tanh_f(float x) {
  return fmaf(2.0f, rcpf(1.0f + __expf(-2.0f * x)), -1.0f);
}

// Pack weights f32->f16 (layouts identical to R3, verified):
// PA[(r*8+c8)*512+t]      = Whh[(t>>2)*8 + r     ][(t&3)*64 + c8*8 ..+8]  r=0..3
//                           (r=0,1 -> VGPR-pinned; r=2,3 -> staged to LDS)
// PB[(c*8+r2*2+hf)*512+t] = Whh[(t>>2)*8+4+r2    ][(t&3)*64 + c*16 + hf*8 ..+8] (streamed)
// PIH[(c*8+r)*512+t]      = Wih[(t>>2)*8 + r     ][(t&3)*32 + c*8 ..+8]  (px kernel)
__global__ void conv_w_kernel(const float* __restrict__ Whh, const float* __restrict__ Wih,
                              uint4* __restrict__ PA, uint4* __restrict__ PB,
                              uint4* __restrict__ PIH) {
  int o = blockIdx.x * 256 + threadIdx.x;
  union { uint4 u; __half h[8]; } p;
  if (o < 16384) {
    int t = o & 511, rc = o >> 9, r = rc >> 3, c8 = rc & 7;
    int j = ((t >> 2) << 3) + r, k = ((t & 3) << 6) + c8 * 8;
    const float* s = Whh + j * NH + k;
#pragma unroll
    for (int i = 0; i < 8; ++i) p.h[i] = __float2half(s[i]);
    PA[o] = p.u;
  } else if (o < 32768) {
    int o2 = o - 16384;
    int t = o2 & 511, rc = o2 >> 9, c = rc >> 3, r2 = (rc >> 1) & 3, hf = rc & 1;
    int j = ((t >> 2) << 3) + 4 + r2, k = ((t & 3) << 6) + c * 16 + hf * 8;
    const float* s = Whh + j * NH + k;
#pragma unroll
    for (int i = 0; i < 8; ++i) p.h[i] = __float2half(s[i]);
    PB[o2] = p.u;
  } else if (o < 49152) {
    int o3 = o - 32768;
    int t = o3 & 511, rc = o3 >> 9, c = rc >> 3, r = rc & 7;
    int j = ((t >> 2) << 3) + r, k = ((t & 3) << 5) + c * 8;
    const float* s = Wih + j * ND + k;
#pragma unroll
    for (int i = 0; i < 8; ++i) p.h[i] = __float2half(s[i]);
    PIH[o3] = p.u;
  }
}

// px kernel: unchanged from R2/R3 (verified).
__global__ __launch_bounds__(512, 2)
void px_kernel(const float* __restrict__ xv, const float* __restrict__ xl,
               const float* __restrict__ xu, const uint4* __restrict__ PIH,
               __half* __restrict__ px) {
  __shared__ __align__(16) __half sv[32 * ND];
  __shared__ __align__(16) __half sm[32 * ND];
  __shared__ __align__(16) __half sr[32 * ND];
  const int t = threadIdx.x;
  const int q = t & 3;
  const int r0 = blockIdx.x * 32;
  uint4 w[4][8];
#pragma unroll
  for (int c = 0; c < 4; ++c)
#pragma unroll
    for (int r = 0; r < 8; ++r)
      w[c][r] = PIH[((c * 8 + r) << 9) + t];
  {
    const float4* v4 = (const float4*)(xv + (size_t)r0 * ND);
    const float4* l4 = (const float4*)(xl + (size_t)r0 * ND);
    const float4* u4 = (const float4*)(xu + (size_t)r0 * ND);
    __half2* sv2 = (__half2*)sv; __half2* sm2 = (__half2*)sm; __half2* sr2 = (__half2*)sr;
    for (int i = t; i < 1024; i += 512) {
      float4 v = v4[i], l = l4[i], u = u4[i];
      sv2[2*i]   = __floats2half2_rn(v.x, v.y);
      sv2[2*i+1] = __floats2half2_rn(v.z, v.w);
      sm2[2*i]   = __floats2half2_rn(0.5f*(l.x+u.x), 0.5f*(l.y+u.y));
      sm2[2*i+1] = __floats2half2_rn(0.5f*(l.z+u.z), 0.5f*(l.w+u.w));
      sr2[2*i]   = __floats2half2_rn(0.5f*(u.x-l.x), 0.5f*(u.y-l.y));
      sr2[2*i+1] = __floats2half2_rn(0.5f*(u.z-l.z), 0.5f*(u.w-l.w));
    }
  }
  __syncthreads();
  const uint4* bv = (const uint4*)sv;
  const uint4* bm = (const uint4*)sm;
  const uint4* br = (const uint4*)sr;
  for (int rr = 0; rr < 32; ++rr) {
    uint4 hv[4], hm[4], hr[4];
    const int base = rr * 16 + q * 4;
#pragma unroll
    for (int i = 0; i < 4; ++i) { hv[i] = bv[base+i]; hm[i] = bm[base+i]; hr[i] = br[base+i]; }
    float A[8][3];
#pragma unroll
    for (int r = 0; r < 8; ++r) { A[r][0] = 0.f; A[r][1] = 0.f; A[r][2] = 0.f; }
#pragma unroll
    for (int c = 0; c < 4; ++c)
#pragma unroll
      for (int r = 0; r < 8; ++r)
        acc8(w[c][r], hv[c], hm[c], hr[c], A[r][0], A[r][1], A[r][2]);
#pragma unroll
    for (int r = 0; r < 8; ++r) {
      A[r][0] = qsum4(A[r][0]); A[r][1] = qsum4(A[r][1]); A[r][2] = qsum4(A[r][2]);
    }
    float v0 = sel4(A[0][0], A[2][0], A[4][0], A[6][0], q);
    float m0 = sel4(A[0][1], A[2][1], A[4][1], A[6][1], q);
    float d0 = sel4(A[0][2], A[2][2], A[4][2], A[6][2], q);
    float v1 = sel4(A[1][0], A[3][0], A[5][0], A[7][0], q);
    float m1 = sel4(A[1][1], A[3][1], A[5][1], A[7][1], q);
    float d1 = sel4(A[1][2], A[3][2], A[5][2], A[7][2], q);
    size_t ob = (size_t)(r0 + rr) * G4;
    ((__half2*)(px + ob))[t]             = __floats2half2_rn(v0, v1);
    ((__half2*)(px + CSTRIDE + ob))[t]   = __floats2half2_rn(m0 - d0, m1 - d1);
    ((__half2*)(px + 2*CSTRIDE + ob))[t] = __floats2half2_rn(m0 + d0, m1 + d1);
  }
}

// Recurrence: one block/batch row, 512 threads, q=t&3 K-quarter, g=t>>2 row-octet.
// W tiers per thread-row r (j = g*8+r):
//   r=0,1  VGPR-pinned via asm (64 regs; compiler can't rematerialize)
//   r=2,3  LDS-resident (128 KiB, staged once; lane-consecutive ds_read_b128)
//   r=4..7 streamed from L2 per step (256 KiB/block/step)
// px double-buffered; out-stores deferred past the 2nd barrier (drain hides
// under next step's GEMV instead of the serial tail).
__global__ __launch_bounds__(512, 2)
void lstm_kernel(const uint4* __restrict__ PA, const uint4* __restrict__ PB,
                 const __half* __restrict__ px, const float* __restrict__ bias,
                 float* __restrict__ out) {
  __shared__ uint4 sLW[8192];                     // 128 KiB: W rows r=2,3
  __shared__ __align__(16) __half sH[3][4][72];   // [comp][q][64 + 8 pad]
  __shared__ __align__(16) float sG[3][G4];       // activated gates
  const int t = threadIdx.x;
  const int b = blockIdx.x;
  const int q = t & 3;
  const int g = t >> 2;
  // ---- VGPR-pinned W rows r=0,1 ----
  uint4 Wv[2][8];
#pragma unroll
  for (int r = 0; r < 2; ++r)
#pragma unroll
    for (int c8 = 0; c8 < 8; ++c8)
      Wv[r][c8] = PA[((r * 8 + c8) << 9) + t];
#pragma unroll
  for (int r = 0; r < 2; ++r)
#pragma unroll
    for (int c8 = 0; c8 < 8; ++c8)
      asm volatile("" : "+v"(Wv[r][c8].x), "+v"(Wv[r][c8].y),
                        "+v"(Wv[r][c8].z), "+v"(Wv[r][c8].w));
  // ---- stage W rows r=2,3 into LDS ----
#pragma unroll
  for (int x = 0; x < 16; ++x)
    sLW[(x << 9) + t] = PA[((16 + x) << 9) + t];
  const float2 bb = ((const float2*)bias)[g * 4 + q];  // bias rows g*8+2q, +1
  const bool is_tanh = ((g >> 5) == 2);                // rows 512..767 = gate g
  if (t < 432) ((unsigned*)sH)[t] = 0u;                // zero h (1728 B)
  float cv = 0.f, cl = 0.f, cu = 0.f;                  // cell state (t<256)
  __syncthreads();
  const __half* pxb = px + (size_t)b * NT * G4 + g * 8;
  float* outb = out + (size_t)b * NT * NH;
  // px current (double-buffered)
  uint4 pxV = *(const uint4*)(pxb);
  uint4 pxL = *(const uint4*)(pxb + CSTRIDE);
  uint4 pxU = *(const uint4*)(pxb + 2 * CSTRIDE);
  float hv_p = 0.f, hl_p = 0.f, hu_p = 0.f;            // deferred out values
  for (int ts = 0; ts < NT; ++ts) {
    // deferred store of step ts-1 (fires early, drains under this GEMV)
    if (ts > 0 && t < NH) {
      size_t o = (size_t)(ts - 1) * NH + t;
      outb[o] = hv_p; outb[OSTRIDE + o] = hl_p; outb[2 * OSTRIDE + o] = hu_p;
    }
    // prefetch next step's px
    const int tsn = (ts + 1 < NT) ? ts + 1 : ts;
    const __half* pxn = pxb + (size_t)tsn * G4;
    uint4 nV = *(const uint4*)(pxn);
    uint4 nL = *(const uint4*)(pxn + CSTRIDE);
    uint4 nU = *(const uint4*)(pxn + 2 * CSTRIDE);
    float A[8][3];
#pragma unroll
    for (int r = 0; r < 8; ++r) { A[r][0] = 0.f; A[r][1] = 0.f; A[r][2] = 0.f; }
#pragma unroll
    for (int c = 0; c < 4; ++c) {                      // 16-h chunks of K-quarter
      // streamed rows r=4..7
      uint4 wb[4][2];
#pragma unroll
      for (int r2 = 0; r2 < 4; ++r2) {
        wb[r2][0] = PB[((c * 8 + r2 * 2 + 0) << 9) + t];
        wb[r2][1] = PB[((c * 8 + r2 * 2 + 1) << 9) + t];
      }
      // LDS rows r=2,3 (lane-consecutive b128, conflict-free)
      uint4 wl[2][2];
#pragma unroll
      for (int r2 = 0; r2 < 2; ++r2) {
        wl[r2][0] = sLW[((r2 * 8 + c * 2 + 0) << 9) + t];
        wl[r2][1] = sLW[((r2 * 8 + c * 2 + 1) << 9) + t];
      }
      // h chunk (quad-broadcast from q-slice)
      const uint4* hv4 = (const uint4*)(&sH[0][q][0]) + c * 2;
      const uint4* hm4 = (const uint4*)(&sH[1][q][0]) + c * 2;
      const uint4* hr4 = (const uint4*)(&sH[2][q][0]) + c * 2;
      uint4 hv0 = hv4[0], hv1 = hv4[1];
      uint4 hm0 = hm4[0], hm1 = hm4[1];
      uint4 hr0 = hr4[0], hr1 = hr4[1];
      // pinned rows first (covers load latency of wb/wl)
#pragma unroll
      for (int r = 0; r < 2; ++r) {
        acc8(Wv[r][c * 2 + 0], hv0, hm0, hr0, A[r][0], A[r][1], A[r][2]);
        acc8(Wv[r][c * 2 + 1], hv1, hm1, hr1, A[r][0], A[r][1], A[r][2]);
      }
#pragma unroll
      for (int r2 = 0; r2 < 2; ++r2) {
        acc8(wl[r2][0], hv0, hm0, hr0, A[2 + r2][0], A[2 + r2][1], A[2 + r2][2]);
        acc8(wl[r2][1], hv1, hm1, hr1, A[2 + r2][0], A[2 + r2][1], A[2 + r2][2]);
      }
#pragma unroll
      for (int r2 = 0; r2 < 4; ++r2) {
        acc8(wb[r2][0], hv0, hm0, hr0, A[4 + r2][0], A[4 + r2][1], A[4 + r2][2]);
        acc8(wb[r2][1], hv1, hm1, hr1, A[4 + r2][0], A[4 + r2][1], A[4 + r2][2]);
      }
    }
#pragma unroll
    for (int r = 0; r < 8; ++r) {
      A[r][0] = qsum4(A[r][0]); A[r][1] = qsum4(A[r][1]); A[r][2] = qsum4(A[r][2]);
    }
    // writer rows w0 = g*8+2q, w1 = w0+1
    float v0 = sel4(A[0][0], A[2][0], A[4][0], A[6][0], q);
    float m0 = sel4(A[0][1], A[2][1], A[4][1], A[6][1], q);
    float d0 = sel4(A[0][2], A[2][2], A[4][2], A[6][2], q);
    float v1 = sel4(A[1][0], A[3][0], A[5][0], A[7][0], q);
    float m1 = sel4(A[1][1], A[3][1], A[5][1], A[7][1], q);
    float d1 = sel4(A[1][2], A[3][2], A[5][2], A[7][2], q);
    __half2 pv2 = __builtin_bit_cast(__half2, usel4(pxV.x, pxV.y, pxV.z, pxV.w, q));
    __half2 pl2 = __builtin_bit_cast(__half2, usel4(pxL.x, pxL.y, pxL.z, pxL.w, q));
    __half2 pu2 = __builtin_bit_cast(__half2, usel4(pxU.x, pxU.y, pxU.z, pxU.w, q));
    float g00 = gact(__low2float(pv2)  + bb.x + v0, is_tanh);
    float g01 = gact(__low2float(pl2)  + bb.x + (m0 - d0), is_tanh);
    float g02 = gact(__low2float(pu2)  + bb.x + (m0 + d0), is_tanh);
    float g10 = gact(__high2float(pv2) + bb.y + v1, is_tanh);
    float g11 = gact(__high2float(pl2) + bb.y + (m1 - d1), is_tanh);
    float g12 = gact(__high2float(pu2) + bb.y + (m1 + d1), is_tanh);
    const int wi = g * 4 + q;
    ((float2*)&sG[0][0])[wi] = make_float2(g00, g10);
    ((float2*)&sG[1][0])[wi] = make_float2(g01, g11);
    ((float2*)&sG[2][0])[wi] = make_float2(g02, g12);
    __syncthreads();
    if (t < NH) {
      float iv = sG[0][t],        il = sG[1][t],        iu = sG[2][t];
      float fv = sG[0][NH+t],     fl = sG[1][NH+t],     fu = sG[2][NH+t];
      float gv = sG[0][2*NH+t],   gl = sG[1][2*NH+t],   gu = sG[2][2*NH+t];
      float ov = sG[0][3*NH+t],   ol = sG[1][3*NH+t],   ou = sG[2][3*NH+t];
      float p0 = fl*cl, p1 = fl*cu, p2 = fu*cl, p3 = fu*cu;
      float fcl = fminf(fminf(p0,p1), fminf(p2,p3));
      float fcu = fmaxf(fmaxf(p0,p1), fmaxf(p2,p3));
      float fcv = fv*cv;
      p0 = il*gl; p1 = il*gu; p2 = iu*gl; p3 = iu*gu;
      float igl = fminf(fminf(p0,p1), fminf(p2,p3));
      float igu = fmaxf(fmaxf(p0,p1), fmaxf(p2,p3));
      cv = fcv + iv*gv; cl = fcl + igl; cu = fcu + igu;
      float tv = tanh_f(cv), tl = tanh_f(cl), tu = tanh_f(cu);
      float hvn = ov*tv;
      p0 = ol*tl; p1 = ol*tu; p2 = ou*tl; p3 = ou*tu;
      float hl = fminf(fminf(p0,p1), fminf(p2,p3));
      float hu = fmaxf(fmaxf(p0,p1), fmaxf(p2,p3));
      hv_p = hvn; hl_p = hl; hu_p = hu;                // store deferred
      const int hq = t >> 6, ho = t & 63;
      sH[0][hq][ho] = __float2half(hvn);
      sH[1][hq][ho] = __float2half(0.5f * (hl + hu));
      sH[2][hq][ho] = __float2half(0.5f * (hu - hl));
    }
    __syncthreads();
    pxV = nV; pxL = nL; pxU = nU;                      // rotate px buffers
  }
  if (t < NH) {                                        // final deferred store
    size_t o = (size_t)(NT - 1) * NH + t;
    outb[o] = hv_p; outb[OSTRIDE + o] = hl_p; outb[2 * OSTRIDE + o] = hu_p;
  }
}

extern "C" void kernel_launch(void* const* d_in, const int* in_sizes, int n_in,
                              void* d_out, int out_size, void* d_ws, size_t ws_size,
                              hipStream_t stream) {
  const float* xv   = (const float*)d_in[0];
  const float* xl   = (const float*)d_in[1];
  const float* xu   = (const float*)d_in[2];
  const float* Wih  = (const float*)d_in[3];
  const float* Whh  = (const float*)d_in[4];
  const float* bias = (const float*)d_in[5];
  float* out = (float*)d_out;
  char* ws = (char*)d_ws;
  uint4*  PA  = (uint4*)ws;                    // 256 KiB (r=0..3: pinned + LDS-staged)
  uint4*  PB  = (uint4*)(ws + 256 * 1024);     // 256 KiB (streamed rows)
  uint4*  PIH = (uint4*)(ws + 512 * 1024);     // 256 KiB (px weights)
  __half* px  = (__half*)(ws + 768 * 1024);    // 192 MiB

  conv_w_kernel<<<192, 256, 0, stream>>>(Whh, Wih, PA, PB, PIH);
  px_kernel<<<NBT / 32, 512, 0, stream>>>(xv, xl, xu, PIH, px);
  lstm_kernel<<<NB, 512, 0, stream>>>(PA, PB, px, bias, out);
}

// Round 5
// 2568.993 us; speedup vs baseline: 1.9064x; 1.1595x over previous
//
#include <hip/hip_runtime.h>
#include <hip/hip_fp16.h>

#define NB 64
#define NT 512
#define ND 128
#define NH 256
#define G4 1024                     // 4*H
#define NBT (NB*NT)                 // 32768
#define CSTRIDE ((size_t)NBT * G4)  // elements per interval component of px
#define OSTRIDE ((size_t)NBT * NH)  // elements per interval component of out

typedef _Float16 f16x2 __attribute__((ext_vector_type(2)));

__device__ __forceinline__ float fdot2u(unsigned a, unsigned b, float c) {
  return __builtin_amdgcn_fdot2(__builtin_bit_cast(f16x2, a),
                                __builtin_bit_cast(f16x2, b), c, false);
}

// val-only: 4 fdot2
__device__ __forceinline__ void accV(uint4 w, uint4 hv, float& av) {
  av = fdot2u(w.x, hv.x, av);
  av = fdot2u(w.y, hv.y, av);
  av = fdot2u(w.z, hv.z, av);
  av = fdot2u(w.w, hv.w, av);
}
// interval: mid += w.hm, rad += |w|.hr
__device__ __forceinline__ void accMR(uint4 w, uint4 hm, uint4 hr, float& am, float& ar) {
  const unsigned M = 0x7FFF7FFFu;
  am = fdot2u(w.x, hm.x, am); ar = fdot2u(w.x & M, hr.x, ar);
  am = fdot2u(w.y, hm.y, am); ar = fdot2u(w.y & M, hr.y, ar);
  am = fdot2u(w.z, hm.z, am); ar = fdot2u(w.z & M, hr.z, ar);
  am = fdot2u(w.w, hm.w, am); ar = fdot2u(w.w & M, hr.w, ar);
}

// quad all-reduce via DPP quad_perm (verified R2-R4)
__device__ __forceinline__ float qsum4(float x) {
  int v = __builtin_amdgcn_update_dpp(0, __builtin_bit_cast(int, x), 0xB1, 0xF, 0xF, true);
  x += __builtin_bit_cast(float, v);
  v = __builtin_amdgcn_update_dpp(0, __builtin_bit_cast(int, x), 0x4E, 0xF, 0xF, true);
  x += __builtin_bit_cast(float, v);
  return x;
}
__device__ __forceinline__ float sel4(float x0, float x1, float x2, float x3, int q) {
  float a = (q & 1) ? x1 : x0;
  float b = (q & 1) ? x3 : x2;
  return (q & 2) ? b : a;
}

__device__ __forceinline__ float rcpf(float x) { return __builtin_amdgcn_rcpf(x); }
__device__ __forceinline__ float gact(float x, bool is_tanh) {
  float s = is_tanh ? -2.0f : -1.0f;
  float e = __expf(s * x);
  float r = rcpf(1.0f + e);
  return is_tanh ? fmaf(2.0f, r, -1.0f) : r;
}
__device__ __forceinline__ float tanh_f(float x) {
  return fmaf(2.0f, rcpf(1.0f + __expf(-2.0f * x)), -1.0f);
}

// Pack weights f32->f16.
// P4[(r*8+c8)*1024 + t] = Whh[j=(t>>2)*4 + r][k=(t&3)*64 + c8*8 ..+8], r=0..3, c8=0..7
//   (r=0,1 VGPR-pinned; r=2 LDS; r=3 streamed)
// PIH[(c*8+r)*512 + t]  = Wih[(t>>2)*8 + r][(t&3)*32 + c*8 ..+8]  (px kernel, verified R2-R4)
__global__ void conv_w_kernel(const float* __restrict__ Whh, const float* __restrict__ Wih,
                              uint4* __restrict__ P4, uint4* __restrict__ PIH) {
  int o = blockIdx.x * 256 + threadIdx.x;
  union { uint4 u; __half h[8]; } p;
  if (o < 32768) {
    int t = o & 1023, rc = o >> 10, r = rc >> 3, c8 = rc & 7;
    int j = ((t >> 2) << 2) + r, k = ((t & 3) << 6) + c8 * 8;
    const float* s = Whh + j * NH + k;
#pragma unroll
    for (int i = 0; i < 8; ++i) p.h[i] = __float2half(s[i]);
    P4[o] = p.u;
  } else if (o < 49152) {
    int o3 = o - 32768;
    int t = o3 & 511, rc = o3 >> 9, c = rc >> 3, r = rc & 7;
    int j = ((t >> 2) << 3) + r, k = ((t & 3) << 5) + c * 8;
    const float* s = Wih + j * ND + k;
#pragma unroll
    for (int i = 0; i < 8; ++i) p.h[i] = __float2half(s[i]);
    PIH[o3] = p.u;
  }
}

// px kernel: unchanged from R2-R4 (verified).
__global__ __launch_bounds__(512, 2)
void px_kernel(const float* __restrict__ xv, const float* __restrict__ xl,
               const float* __restrict__ xu, const uint4* __restrict__ PIH,
               __half* __restrict__ px) {
  __shared__ __align__(16) __half sv[32 * ND];
  __shared__ __align__(16) __half sm[32 * ND];
  __shared__ __align__(16) __half sr[32 * ND];
  const int t = threadIdx.x;
  const int q = t & 3;
  const int r0 = blockIdx.x * 32;
  uint4 w[4][8];
#pragma unroll
  for (int c = 0; c < 4; ++c)
#pragma unroll
    for (int r = 0; r < 8; ++r)
      w[c][r] = PIH[((c * 8 + r) << 9) + t];
  {
    const float4* v4 = (const float4*)(xv + (size_t)r0 * ND);
    const float4* l4 = (const float4*)(xl + (size_t)r0 * ND);
    const float4* u4 = (const float4*)(xu + (size_t)r0 * ND);
    __half2* sv2 = (__half2*)sv; __half2* sm2 = (__half2*)sm; __half2* sr2 = (__half2*)sr;
    for (int i = t; i < 1024; i += 512) {
      float4 v = v4[i], l = l4[i], u = u4[i];
      sv2[2*i]   = __floats2half2_rn(v.x, v.y);
      sv2[2*i+1] = __floats2half2_rn(v.z, v.w);
      sm2[2*i]   = __floats2half2_rn(0.5f*(l.x+u.x), 0.5f*(l.y+u.y));
      sm2[2*i+1] = __floats2half2_rn(0.5f*(l.z+u.z), 0.5f*(l.w+u.w));
      sr2[2*i]   = __floats2half2_rn(0.5f*(u.x-l.x), 0.5f*(u.y-l.y));
      sr2[2*i+1] = __floats2half2_rn(0.5f*(u.z-l.z), 0.5f*(u.w-l.w));
    }
  }
  __syncthreads();
  const uint4* bv = (const uint4*)sv;
  const uint4* bm = (const uint4*)sm;
  const uint4* br = (const uint4*)sr;
  for (int rr = 0; rr < 32; ++rr) {
    uint4 hv[4], hm[4], hr[4];
    const int base = rr * 16 + q * 4;
#pragma unroll
    for (int i = 0; i < 4; ++i) { hv[i] = bv[base+i]; hm[i] = bm[base+i]; hr[i] = br[base+i]; }
    float A[8][3];
#pragma unroll
    for (int r = 0; r < 8; ++r) { A[r][0] = 0.f; A[r][1] = 0.f; A[r][2] = 0.f; }
#pragma unroll
    for (int c = 0; c < 4; ++c)
#pragma unroll
      for (int r = 0; r < 8; ++r) {
        accV(w[c][r], hv[c], A[r][0]);
        accMR(w[c][r], hm[c], hr[c], A[r][1], A[r][2]);
      }
#pragma unroll
    for (int r = 0; r < 8; ++r) {
      A[r][0] = qsum4(A[r][0]); A[r][1] = qsum4(A[r][1]); A[r][2] = qsum4(A[r][2]);
    }
    float v0 = sel4(A[0][0], A[2][0], A[4][0], A[6][0], q);
    float m0 = sel4(A[0][1], A[2][1], A[4][1], A[6][1], q);
    float d0 = sel4(A[0][2], A[2][2], A[4][2], A[6][2], q);
    float v1 = sel4(A[1][0], A[3][0], A[5][0], A[7][0], q);
    float m1 = sel4(A[1][1], A[3][1], A[5][1], A[7][1], q);
    float d1 = sel4(A[1][2], A[3][2], A[5][2], A[7][2], q);
    size_t ob = (size_t)(r0 + rr) * G4;
    ((__half2*)(px + ob))[t]             = __floats2half2_rn(v0, v1);
    ((__half2*)(px + CSTRIDE + ob))[t]   = __floats2half2_rn(m0 - d0, m1 - d1);
    ((__half2*)(px + 2*CSTRIDE + ob))[t] = __floats2half2_rn(m0 + d0, m1 + d1);
  }
}

// Recurrence, split into two independent recurrences (val path / interval path):
// 128 blocks: blockIdx<64 -> val LSTM for batch row b; >=64 -> interval LSTM.
// 1024 threads: q=t&3 K-quarter, 4 rows/thread (j = (t>>2)*4+r); after quad
// reduce+sel4 thread t owns gate row t exactly (px/bias/sG accesses = [t]).
// W tiers: r=0,1 VGPR-pinned (64 regs, asm), r=2 LDS (128 KiB), r=3 streamed
// (128 KiB/step). px double-buffered; out stores deferred one step.
__global__ __launch_bounds__(1024, 4)
void lstm_kernel(const uint4* __restrict__ P4, const __half* __restrict__ px,
                 const float* __restrict__ bias, float* __restrict__ out) {
  __shared__ uint4 sLW[8192];                     // 128 KiB: W row-index r=2
  __shared__ __align__(16) __half sH[2][4][72];   // [slot][q][64+8 pad]; val: slot0=hv; intv: 0=hm,1=hr
  __shared__ __align__(16) float sG[2][G4];       // val: slot0; intv: 0=g_lb, 1=g_ub
  const int t = threadIdx.x;
  const bool intv = blockIdx.x >= NB;
  const int b = intv ? blockIdx.x - NB : blockIdx.x;
  const int q = t & 3;
  // pinned W rows r=0,1
  uint4 Wp[2][8];
#pragma unroll
  for (int r = 0; r < 2; ++r)
#pragma unroll
    for (int c8 = 0; c8 < 8; ++c8)
      Wp[r][c8] = P4[((r * 8 + c8) << 10) + t];
#pragma unroll
  for (int r = 0; r < 2; ++r)
#pragma unroll
    for (int c8 = 0; c8 < 8; ++c8)
      asm volatile("" : "+v"(Wp[r][c8].x), "+v"(Wp[r][c8].y),
                        "+v"(Wp[r][c8].z), "+v"(Wp[r][c8].w));
  // stage r=2 into LDS
#pragma unroll
  for (int c8 = 0; c8 < 8; ++c8)
    sLW[(c8 << 10) + t] = P4[((16 + c8) << 10) + t];
  const float bt_ = bias[t];
  const bool is_tanh = ((t >> 8) == 2);           // rows 512..767 = gate g
  if (t < 288) ((unsigned*)sH)[t] = 0u;           // zero h (1152 B)
  __syncthreads();
  const __half* pxb = px + (size_t)b * NT * G4;
  float* outb = out + (size_t)b * NT * NH;

  if (!intv) {
    // ---------------- point-value LSTM ----------------
    float cv = 0.f, hv_p = 0.f;
    float pv = __half2float(pxb[t]);
    for (int ts = 0; ts < NT; ++ts) {
      if (ts > 0 && t < NH) outb[(size_t)(ts - 1) * NH + t] = hv_p;
      const int tsn = (ts + 1 < NT) ? ts + 1 : ts;
      float nv = __half2float(pxb[(size_t)tsn * G4 + t]);
      float A0 = 0.f, A1 = 0.f, A2 = 0.f, A3 = 0.f;
#pragma unroll
      for (int c8 = 0; c8 < 8; ++c8) {
        uint4 ws3 = P4[((24 + c8) << 10) + t];          // streamed r=3
        uint4 wl2 = sLW[(c8 << 10) + t];                // LDS r=2
        uint4 hv = *(const uint4*)(&sH[0][q][c8 * 8]);  // quad-distinct broadcast
        accV(Wp[0][c8], hv, A0);
        accV(Wp[1][c8], hv, A1);
        accV(wl2, hv, A2);
        accV(ws3, hv, A3);
      }
      A0 = qsum4(A0); A1 = qsum4(A1); A2 = qsum4(A2); A3 = qsum4(A3);
      float av = sel4(A0, A1, A2, A3, q);               // row t
      float gt = gact(pv + bt_ + av, is_tanh);
      sG[0][t] = gt;
      __syncthreads();
      if (t < NH) {
        float iv = sG[0][t], fv = sG[0][NH + t], gv = sG[0][2 * NH + t], ov = sG[0][3 * NH + t];
        cv = fmaf(fv, cv, iv * gv);
        float hvn = ov * tanh_f(cv);
        hv_p = hvn;
        sH[0][t >> 6][t & 63] = __float2half(hvn);
      }
      __syncthreads();
      pv = nv;
    }
    if (t < NH) outb[(size_t)(NT - 1) * NH + t] = hv_p;
  } else {
    // ---------------- interval (lb/ub) LSTM ----------------
    float cl = 0.f, cu = 0.f, hl_p = 0.f, hu_p = 0.f;
    float pl = __half2float(pxb[CSTRIDE + t]);
    float pu = __half2float(pxb[2 * CSTRIDE + t]);
    for (int ts = 0; ts < NT; ++ts) {
      if (ts > 0 && t < NH) {
        size_t o = (size_t)(ts - 1) * NH + t;
        outb[OSTRIDE + o] = hl_p; outb[2 * OSTRIDE + o] = hu_p;
      }
      const int tsn = (ts + 1 < NT) ? ts + 1 : ts;
      float nl = __half2float(pxb[(size_t)tsn * G4 + CSTRIDE + t]);
      float nu = __half2float(pxb[(size_t)tsn * G4 + 2 * CSTRIDE + t]);
      float M0 = 0.f, M1 = 0.f, M2 = 0.f, M3 = 0.f;
      float R0 = 0.f, R1 = 0.f, R2 = 0.f, R3 = 0.f;
#pragma unroll
      for (int c8 = 0; c8 < 8; ++c8) {
        uint4 ws3 = P4[((24 + c8) << 10) + t];
        uint4 wl2 = sLW[(c8 << 10) + t];
        uint4 hm = *(const uint4*)(&sH[0][q][c8 * 8]);
        uint4 hr = *(const uint4*)(&sH[1][q][c8 * 8]);
        accMR(Wp[0][c8], hm, hr, M0, R0);
        accMR(Wp[1][c8], hm, hr, M1, R1);
        accMR(wl2, hm, hr, M2, R2);
        accMR(ws3, hm, hr, M3, R3);
      }
      M0 = qsum4(M0); M1 = qsum4(M1); M2 = qsum4(M2); M3 = qsum4(M3);
      R0 = qsum4(R0); R1 = qsum4(R1); R2 = qsum4(R2); R3 = qsum4(R3);
      float m = sel4(M0, M1, M2, M3, q);                // row t
      float d = sel4(R0, R1, R2, R3, q);
      float gl = gact(pl + bt_ + (m - d), is_tanh);
      float gu = gact(pu + bt_ + (m + d), is_tanh);
      sG[0][t] = gl; sG[1][t] = gu;
      __syncthreads();
      if (t < NH) {
        float il = sG[0][t],        iu = sG[1][t];
        float fl = sG[0][NH+t],     fu = sG[1][NH+t];
        float gl_ = sG[0][2*NH+t],  gu_ = sG[1][2*NH+t];
        float ol = sG[0][3*NH+t],   ou = sG[1][3*NH+t];
        float p0 = fl*cl, p1 = fl*cu, p2 = fu*cl, p3 = fu*cu;
        float fcl = fminf(fminf(p0,p1), fminf(p2,p3));
        float fcu = fmaxf(fmaxf(p0,p1), fmaxf(p2,p3));
        p0 = il*gl_; p1 = il*gu_; p2 = iu*gl_; p3 = iu*gu_;
        float igl = fminf(fminf(p0,p1), fminf(p2,p3));
        float igu = fmaxf(fmaxf(p0,p1), fmaxf(p2,p3));
        cl = fcl + igl; cu = fcu + igu;
        float tl = tanh_f(cl), tu = tanh_f(cu);
        p0 = ol*tl; p1 = ol*tu; p2 = ou*tl; p3 = ou*tu;
        float hl = fminf(fminf(p0,p1), fminf(p2,p3));
        float hu = fmaxf(fmaxf(p0,p1), fmaxf(p2,p3));
        hl_p = hl; hu_p = hu;
        sH[0][t >> 6][t & 63] = __float2half(0.5f * (hl + hu));
        sH[1][t >> 6][t & 63] = __float2half(0.5f * (hu - hl));
      }
      __syncthreads();
      pl = nl; pu = nu;
    }
    if (t < NH) {
      size_t o = (size_t)(NT - 1) * NH + t;
      outb[OSTRIDE + o] = hl_p; outb[2 * OSTRIDE + o] = hu_p;
    }
  }
}

extern "C" void kernel_launch(void* const* d_in, const int* in_sizes, int n_in,
                              void* d_out, int out_size, void* d_ws, size_t ws_size,
                              hipStream_t stream) {
  const float* xv   = (const float*)d_in[0];
  const float* xl   = (const float*)d_in[1];
  const float* xu   = (const float*)d_in[2];
  const float* Wih  = (const float*)d_in[3];
  const float* Whh  = (const float*)d_in[4];
  const float* bias = (const float*)d_in[5];
  float* out = (float*)d_out;
  char* ws = (char*)d_ws;
  uint4*  P4  = (uint4*)ws;                    // 512 KiB (recurrent W, 4-row layout)
  uint4*  PIH = (uint4*)(ws + 512 * 1024);     // 256 KiB (px weights)
  __half* px  = (__half*)(ws + 768 * 1024);    // 192 MiB

  conv_w_kernel<<<192, 256, 0, stream>>>(Whh, Wih, P4, PIH);
  px_kernel<<<NBT / 32, 512, 0, stream>>>(xv, xl, xu, PIH, px);
  lstm_kernel<<<2 * NB, 1024, 0, stream>>>(P4, px, bias, out);
}